// Round 1
// baseline (37.651 us; speedup 1.0000x reference)
//
#include <hip/hip_runtime.h>

typedef __attribute__((ext_vector_type(8))) short short8;
typedef __attribute__((ext_vector_type(4))) float f32x4;

__device__ __forceinline__ unsigned short f2bf(float f) {
    union { float f; unsigned int u; } v; v.f = f;
    unsigned int u = v.u;
    unsigned int r = u + 0x7FFFu + ((u >> 16) & 1u);
    return (unsigned short)(r >> 16);
}

// Kernel A: Wmat[e][c] = sum_d proj_w[e][d] * v_w[d][c], stored bf16 row-major [e][c].
// 256 blocks (one per e), 1024 threads: 4-way split over d, LDS reduce.
__global__ __launch_bounds__(1024) void wmat_kernel(
    const float* __restrict__ v_w, const float* __restrict__ proj_w,
    unsigned short* __restrict__ Wm)
{
    __shared__ float red[4][256];
    const int e  = blockIdx.x;
    const int c  = threadIdx.x & 255;
    const int dq = threadIdx.x >> 8;   // 0..3

    const float* pw = proj_w + e * 256 + dq * 64;   // uniform per block -> s_loads
    const float* vv = v_w + (dq * 64) * 256 + c;

    float acc = 0.f;
#pragma unroll 8
    for (int d = 0; d < 64; ++d)
        acc = fmaf(pw[d], vv[d * 256], acc);

    red[dq][c] = acc;
    __syncthreads();
    if (threadIdx.x < 256) {
        float s = red[0][c] + red[1][c] + red[2][c] + red[3][c];
        Wm[e * 256 + c] = f2bf(s);
    }
}

// Kernel B: one block per (b,h) image row: 64 pixels x 256 channels.
// Phase 1: 3x3 weighted blur -> y (bf16) in XOR-swizzled LDS.
// Phase 2: MFMA GEMM  out[64,256] = y[64,256(K)] @ Wmat^T + proj_b.
__global__ __launch_bounds__(256) void fused_kernel(
    const float* __restrict__ x, const unsigned short* __restrict__ Wm,
    const float* __restrict__ proj_b, float* __restrict__ out)
{
    const int bh = blockIdx.x;        // b*64 + h
    const int b  = bh >> 6;
    const int h  = bh & 63;
    const int t  = threadIdx.x;

    __shared__ unsigned short ylds[64 * 256];   // 32 KB, bf16, swizzled

    const float A1  = (float)(1.0 / 10.71828182845904523536);                 // 1/(e+8)
    const float A0D = (float)(2.71828182845904523536 / 10.71828182845904523536) - A1; // (A0-A1)

    // ---------------- blur phase ----------------
    {
        const int w0 = (t >> 5) * 8;      // 8 strips of 8 pixels
        const int c0 = (t & 31) * 8;      // 32 chunks of 8 channels

        const f32x4 z = {0.f, 0.f, 0.f, 0.f};
        f32x4 acc[8][2];
#pragma unroll
        for (int i = 0; i < 8; ++i) { acc[i][0] = z; acc[i][1] = z; }

        for (int r = h - 1; r <= h + 1; ++r) {
            if (r < 0 || r >= 64) continue;
            const bool top = (r == h - 1);
            const float* xr = x + (((size_t)b * 64 + r) * 64) * 256 + c0;

            f32x4 pm0, pm1, pc0, pc1;
            if (w0 == 0) { pm0 = z; pm1 = z; }
            else {
                pm0 = *(const f32x4*)(xr + (w0 - 1) * 256);
                pm1 = *(const f32x4*)(xr + (w0 - 1) * 256 + 4);
            }
            pc0 = *(const f32x4*)(xr + w0 * 256);
            pc1 = *(const f32x4*)(xr + w0 * 256 + 4);

#pragma unroll
            for (int i = 0; i < 8; ++i) {
                const int wn = w0 + i + 1;
                f32x4 pn0 = z, pn1 = z;
                if (wn < 64) {
                    pn0 = *(const f32x4*)(xr + wn * 256);
                    pn1 = *(const f32x4*)(xr + wn * 256 + 4);
                }
                f32x4 s0 = pm0 + pc0 + pn0;
                f32x4 s1 = pm1 + pc1 + pn1;
                acc[i][0] += A1 * s0;
                acc[i][1] += A1 * s1;
                if (top) {   // tap k=0 extra weight on x[h-1][w-1]
                    acc[i][0] += A0D * pm0;
                    acc[i][1] += A0D * pm1;
                }
                pm0 = pc0; pm1 = pc1; pc0 = pn0; pc1 = pn1;
            }
        }

        // pack to bf16, write swizzled: byte ^= ((w&7)<<4)
#pragma unroll
        for (int i = 0; i < 8; ++i) {
            const int w = w0 + i;
            union { short8 v; unsigned short u[8]; } pk;
#pragma unroll
            for (int j = 0; j < 4; ++j) {
                pk.u[j]     = f2bf(acc[i][0][j]);
                pk.u[4 + j] = f2bf(acc[i][1][j]);
            }
            unsigned baddr = ((unsigned)w * 512u + (unsigned)c0 * 2u) ^ (((unsigned)(w & 7)) << 4);
            *reinterpret_cast<short8*>(reinterpret_cast<char*>(ylds) + baddr) = pk.v;
        }
    }
    __syncthreads();

    // ---------------- GEMM phase ----------------
    {
        const int wave = t >> 6;          // 0..3 -> owns N quarter [wave*64, wave*64+64)
        const int lane = t & 63;
        const int lrow = lane & 15;       // m for A, n for B, col for C/D
        const int lkg  = lane >> 4;       // 0..3 k-group
        const int n_base = wave * 64;

        const f32x4 z = {0.f, 0.f, 0.f, 0.f};
        f32x4 acc2[4][4];
#pragma unroll
        for (int mi = 0; mi < 4; ++mi)
#pragma unroll
            for (int ni = 0; ni < 4; ++ni) acc2[mi][ni] = z;

        for (int k0 = 0; k0 < 256; k0 += 32) {
            const int koff = k0 + lkg * 8;
            short8 a[4], bf[4];
#pragma unroll
            for (int mi = 0; mi < 4; ++mi) {
                const int row = mi * 16 + lrow;
                unsigned baddr = ((unsigned)row * 512u + (unsigned)koff * 2u) ^ (((unsigned)(row & 7)) << 4);
                a[mi] = *reinterpret_cast<const short8*>(reinterpret_cast<const char*>(ylds) + baddr);
            }
#pragma unroll
            for (int ni = 0; ni < 4; ++ni) {
                const int e = n_base + ni * 16 + lrow;
                bf[ni] = *reinterpret_cast<const short8*>(Wm + e * 256 + koff);
            }
#pragma unroll
            for (int mi = 0; mi < 4; ++mi)
#pragma unroll
                for (int ni = 0; ni < 4; ++ni)
                    acc2[mi][ni] = __builtin_amdgcn_mfma_f32_16x16x32_bf16(a[mi], bf[ni], acc2[mi][ni], 0, 0, 0);
        }

        // epilogue: += bias, store fp32
        const size_t outbase = (size_t)bh * 64 * 256;
#pragma unroll
        for (int ni = 0; ni < 4; ++ni) {
            const int e = n_base + ni * 16 + lrow;
            const float bias = proj_b[e];
#pragma unroll
            for (int mi = 0; mi < 4; ++mi) {
                const int wrow = mi * 16 + lkg * 4;
                f32x4 v = acc2[mi][ni];
#pragma unroll
                for (int r = 0; r < 4; ++r)
                    out[outbase + (size_t)(wrow + r) * 256 + e] = v[r] + bias;
            }
        }
    }
}

extern "C" void kernel_launch(void* const* d_in, const int* in_sizes, int n_in,
                              void* d_out, int out_size, void* d_ws, size_t ws_size,
                              hipStream_t stream) {
    const float* x      = (const float*)d_in[0];
    const float* v_w    = (const float*)d_in[1];
    const float* proj_w = (const float*)d_in[2];
    const float* proj_b = (const float*)d_in[3];
    float* out = (float*)d_out;
    unsigned short* Wm = (unsigned short*)d_ws;   // 256*256 bf16 = 128 KB

    wmat_kernel<<<256, 1024, 0, stream>>>(v_w, proj_w, Wm);
    fused_kernel<<<512, 256, 0, stream>>>(x, Wm, proj_b, out);
}

// Round 2
// 37.609 us; speedup vs baseline: 1.0011x; 1.0011x over previous
//
#include <hip/hip_runtime.h>

typedef __attribute__((ext_vector_type(8))) short short8;
typedef __attribute__((ext_vector_type(4))) float f32x4;

__device__ __forceinline__ unsigned short f2bf(float f) {
    union { float f; unsigned int u; } v; v.f = f;
    unsigned int u = v.u;
    unsigned int r = u + 0x7FFFu + ((u >> 16) & 1u);
    return (unsigned short)(r >> 16);
}

// Kernel A: Wmat[e][c] = sum_d proj_w[e][d] * v_w[d][c], bf16 row-major [e][c].
// 64 blocks x 1024 threads; block owns 4 e-rows; d split 4-way (dq), LDS reduce.
// Each v_w load feeds 4 FMAs -> L2 traffic 16 MB instead of 67 MB.
__global__ __launch_bounds__(1024) void wmat_kernel(
    const float* __restrict__ v_w, const float* __restrict__ proj_w,
    unsigned short* __restrict__ Wm)
{
    __shared__ float red[4][4][256];
    const int e0 = blockIdx.x * 4;
    const int c  = threadIdx.x & 255;
    const int dq = threadIdx.x >> 8;   // 0..3

    const float* pw = proj_w + e0 * 256 + dq * 64;  // wave-uniform -> s_loads
    const float* vv = v_w + (dq * 64) * 256 + c;

    float acc[4] = {0.f, 0.f, 0.f, 0.f};
#pragma unroll 8
    for (int d = 0; d < 64; ++d) {
        float v = vv[d * 256];
#pragma unroll
        for (int k = 0; k < 4; ++k)
            acc[k] = fmaf(pw[k * 256 + d], v, acc[k]);
    }
#pragma unroll
    for (int k = 0; k < 4; ++k) red[dq][k][c] = acc[k];
    __syncthreads();
    {
        const int e = threadIdx.x >> 8;   // thread t -> (e = t>>8, c = t&255)
        float s = red[0][e][c] + red[1][e][c] + red[2][e][c] + red[3][e][c];
        Wm[(e0 + e) * 256 + c] = f2bf(s);
    }
}

// Kernel B: one block per (b,h) image row: 64 pixels x 256 channels.
// XCD-chunked blockIdx swizzle: each XCD owns one image -> 3x row re-reads hit L2.
// Phase 1: 3x3 weighted blur -> y (bf16) in XOR-swizzled LDS.
// Phase 2: MFMA GEMM out[64,256] = y @ Wmat^T + proj_b, operand-swapped so the
//          D layout gives each lane 4 consecutive e -> f32x4 nontemporal stores.
__global__ __launch_bounds__(256) void fused_kernel(
    const float* __restrict__ x, const unsigned short* __restrict__ Wm,
    const float* __restrict__ proj_b, float* __restrict__ out)
{
    // 512 blocks = 8 XCDs * 64; hardware maps blockIdx % 8 -> XCD (round-robin).
    // Give XCD i the contiguous bh chunk [64*i, 64*i+64) = image i.
    const int bh = (blockIdx.x & 7) * 64 + (blockIdx.x >> 3);
    const int b  = bh >> 6;
    const int h  = bh & 63;
    const int t  = threadIdx.x;

    __shared__ unsigned short ylds[64 * 256];   // 32 KB, bf16, swizzled

    const float A1  = (float)(1.0 / 10.71828182845904523536);                 // 1/(e+8)
    const float A0D = (float)(2.71828182845904523536 / 10.71828182845904523536) - A1; // A0-A1

    // ---------------- blur phase ----------------
    {
        const int w0 = (t >> 5) * 8;      // 8 strips of 8 pixels
        const int c0 = (t & 31) * 8;      // 32 chunks of 8 channels

        const f32x4 z = {0.f, 0.f, 0.f, 0.f};
        f32x4 acc[8][2];
#pragma unroll
        for (int i = 0; i < 8; ++i) { acc[i][0] = z; acc[i][1] = z; }

        for (int r = h - 1; r <= h + 1; ++r) {
            if (r < 0 || r >= 64) continue;
            const bool top = (r == h - 1);
            const float* xr = x + (((size_t)b * 64 + r) * 64) * 256 + c0;

            f32x4 pm0, pm1, pc0, pc1;
            if (w0 == 0) { pm0 = z; pm1 = z; }
            else {
                pm0 = *(const f32x4*)(xr + (w0 - 1) * 256);
                pm1 = *(const f32x4*)(xr + (w0 - 1) * 256 + 4);
            }
            pc0 = *(const f32x4*)(xr + w0 * 256);
            pc1 = *(const f32x4*)(xr + w0 * 256 + 4);

#pragma unroll
            for (int i = 0; i < 8; ++i) {
                const int wn = w0 + i + 1;
                f32x4 pn0 = z, pn1 = z;
                if (wn < 64) {
                    pn0 = *(const f32x4*)(xr + wn * 256);
                    pn1 = *(const f32x4*)(xr + wn * 256 + 4);
                }
                f32x4 s0 = pm0 + pc0 + pn0;
                f32x4 s1 = pm1 + pc1 + pn1;
                acc[i][0] += A1 * s0;
                acc[i][1] += A1 * s1;
                if (top) {   // tap k=0 extra weight on x[h-1][w-1]
                    acc[i][0] += A0D * pm0;
                    acc[i][1] += A0D * pm1;
                }
                pm0 = pc0; pm1 = pc1; pc0 = pn0; pc1 = pn1;
            }
        }

        // pack to bf16, write swizzled: byte ^= ((w&7)<<4)
#pragma unroll
        for (int i = 0; i < 8; ++i) {
            const int w = w0 + i;
            union { short8 v; unsigned short u[8]; } pk;
#pragma unroll
            for (int j = 0; j < 4; ++j) {
                pk.u[j]     = f2bf(acc[i][0][j]);
                pk.u[4 + j] = f2bf(acc[i][1][j]);
            }
            unsigned baddr = ((unsigned)w * 512u + (unsigned)c0 * 2u) ^ (((unsigned)(w & 7)) << 4);
            *reinterpret_cast<short8*>(reinterpret_cast<char*>(ylds) + baddr) = pk.v;
        }
    }
    __syncthreads();

    // ---------------- GEMM phase ----------------
    {
        const int wave = t >> 6;          // 0..3 -> owns N quarter [wave*64, wave*64+64)
        const int lane = t & 63;
        const int lrow = lane & 15;
        const int lkg  = lane >> 4;       // 0..3 k-group
        const int n_base = wave * 64;

        const f32x4 z = {0.f, 0.f, 0.f, 0.f};
        f32x4 acc2[4][4];                 // [mi(pixel block)][ni(e block)]
#pragma unroll
        for (int mi = 0; mi < 4; ++mi)
#pragma unroll
            for (int ni = 0; ni < 4; ++ni) acc2[mi][ni] = z;

        for (int k0 = 0; k0 < 256; k0 += 32) {
            const int koff = k0 + lkg * 8;
            short8 a[4], bf[4];
#pragma unroll
            for (int mi = 0; mi < 4; ++mi) {
                const int row = mi * 16 + lrow;
                unsigned baddr = ((unsigned)row * 512u + (unsigned)koff * 2u) ^ (((unsigned)(row & 7)) << 4);
                a[mi] = *reinterpret_cast<const short8*>(reinterpret_cast<const char*>(ylds) + baddr);
            }
#pragma unroll
            for (int ni = 0; ni < 4; ++ni) {
                const int e = n_base + ni * 16 + lrow;
                bf[ni] = *reinterpret_cast<const short8*>(Wm + e * 256 + koff);
            }
            // operand-swapped: D = W-frag (A) * y-frag (B) -> D[e][pixel]
            // lane holds rows e = ni*16 + lkg*4 + 0..3 (consecutive!), col pixel = mi*16+lrow
#pragma unroll
            for (int mi = 0; mi < 4; ++mi)
#pragma unroll
                for (int ni = 0; ni < 4; ++ni)
                    acc2[mi][ni] = __builtin_amdgcn_mfma_f32_16x16x32_bf16(bf[ni], a[mi], acc2[mi][ni], 0, 0, 0);
        }

        // epilogue: vector bias + f32x4 nontemporal stores (out is write-only)
        const size_t outbase = (size_t)bh * 64 * 256;
        f32x4 bias4[4];
#pragma unroll
        for (int ni = 0; ni < 4; ++ni)
            bias4[ni] = *reinterpret_cast<const f32x4*>(proj_b + n_base + ni * 16 + lkg * 4);

#pragma unroll
        for (int mi = 0; mi < 4; ++mi) {
            const int pixel = mi * 16 + lrow;
            float* orow = out + outbase + (size_t)pixel * 256 + n_base + lkg * 4;
#pragma unroll
            for (int ni = 0; ni < 4; ++ni) {
                f32x4 v = acc2[mi][ni] + bias4[ni];
                __builtin_nontemporal_store(v, reinterpret_cast<f32x4*>(orow + ni * 16));
            }
        }
    }
}

extern "C" void kernel_launch(void* const* d_in, const int* in_sizes, int n_in,
                              void* d_out, int out_size, void* d_ws, size_t ws_size,
                              hipStream_t stream) {
    const float* x      = (const float*)d_in[0];
    const float* v_w    = (const float*)d_in[1];
    const float* proj_w = (const float*)d_in[2];
    const float* proj_b = (const float*)d_in[3];
    float* out = (float*)d_out;
    unsigned short* Wm = (unsigned short*)d_ws;   // 256*256 bf16 = 128 KB

    wmat_kernel<<<64, 1024, 0, stream>>>(v_w, proj_w, Wm);
    fused_kernel<<<512, 256, 0, stream>>>(x, Wm, proj_b, out);
}

// Round 3
// 35.660 us; speedup vs baseline: 1.0558x; 1.0546x over previous
//
#include <hip/hip_runtime.h>

typedef __attribute__((ext_vector_type(8))) short short8;
typedef __attribute__((ext_vector_type(4))) float f32x4;

__device__ __forceinline__ unsigned short f2bf(float f) {
    union { float f; unsigned int u; } v; v.f = f;
    unsigned int u = v.u;
    unsigned int r = u + 0x7FFFu + ((u >> 16) & 1u);
    return (unsigned short)(r >> 16);
}

// Kernel A: Wmat[e][c] = sum_d proj_w[e][d] * v_w[d][c], bf16 row-major [e][c].
// 256 blocks (one e-row each -> every CU busy) x 1024 threads; d split 4-way, LDS reduce.
__global__ __launch_bounds__(1024) void wmat_kernel(
    const float* __restrict__ v_w, const float* __restrict__ proj_w,
    unsigned short* __restrict__ Wm)
{
    __shared__ float red[4][256];
    const int e  = blockIdx.x;
    const int c  = threadIdx.x & 255;
    const int dq = threadIdx.x >> 8;   // 0..3

    const float* pw = proj_w + e * 256 + dq * 64;   // wave-uniform -> s_loads
    const float* vv = v_w + (dq * 64) * 256 + c;

    float acc = 0.f;
#pragma unroll 8
    for (int d = 0; d < 64; ++d)
        acc = fmaf(pw[d], vv[d * 256], acc);

    red[dq][c] = acc;
    __syncthreads();
    if (threadIdx.x < 256) {
        float s = red[0][c] + red[1][c] + red[2][c] + red[3][c];
        Wm[e * 256 + c] = f2bf(s);
    }
}

// Kernel B: one block per HALF-row: 32 pixels x 256 channels.
// 1024 blocks x 256 threads, 16KB LDS -> 4 blocks/CU (16 waves/CU, 4/SIMD):
// 2x the wave-parallelism of the previous 1-row version, to hide load latency.
// XCD swizzle: 128 consecutive blocks (= 1 image, 4MB = L2 size) per XCD.
__global__ __launch_bounds__(256, 4) void fused_kernel(
    const float* __restrict__ x, const unsigned short* __restrict__ Wm,
    const float* __restrict__ proj_b, float* __restrict__ out)
{
    const int idx   = ((blockIdx.x & 7) << 7) | (blockIdx.x >> 3);  // 1024 = 8*128, bijective
    const int b     = idx >> 7;
    const int h     = (idx >> 1) & 63;
    const int wbase = (idx & 1) * 32;
    const int t     = threadIdx.x;

    __shared__ unsigned short ylds[32 * 256];   // 16 KB, bf16, XOR-swizzled

    const float A1  = (float)(1.0 / 10.71828182845904523536);                 // 1/(e+8)
    const float A0D = (float)(2.71828182845904523536 / 10.71828182845904523536) - A1; // A0-A1

    // ---------------- blur phase (4-pixel strip per thread) ----------------
    {
        const int wl0 = (t >> 5) * 4;     // local strip start in [0,32)
        const int c0  = (t & 31) * 8;     // 8-channel chunk
        const int gw0 = wbase + wl0;      // global pixel of strip start

        const f32x4 z = {0.f, 0.f, 0.f, 0.f};
        f32x4 acc[4][2];
#pragma unroll
        for (int i = 0; i < 4; ++i) { acc[i][0] = z; acc[i][1] = z; }

        for (int r = h - 1; r <= h + 1; ++r) {
            if (r < 0 || r >= 64) continue;
            const bool top = (r == h - 1);
            const float* xr = x + (((size_t)b * 64 + r) * 64) * 256 + c0;

            f32x4 pm0, pm1, pc0, pc1;
            if (gw0 == 0) { pm0 = z; pm1 = z; }
            else {
                pm0 = *(const f32x4*)(xr + (gw0 - 1) * 256);
                pm1 = *(const f32x4*)(xr + (gw0 - 1) * 256 + 4);
            }
            pc0 = *(const f32x4*)(xr + gw0 * 256);
            pc1 = *(const f32x4*)(xr + gw0 * 256 + 4);

#pragma unroll
            for (int i = 0; i < 4; ++i) {
                const int gwn = gw0 + i + 1;
                f32x4 pn0 = z, pn1 = z;
                if (gwn < 64) {
                    pn0 = *(const f32x4*)(xr + gwn * 256);
                    pn1 = *(const f32x4*)(xr + gwn * 256 + 4);
                }
                f32x4 s0 = pm0 + pc0 + pn0;
                f32x4 s1 = pm1 + pc1 + pn1;
                acc[i][0] += A1 * s0;
                acc[i][1] += A1 * s1;
                if (top) {   // tap k=0 extra weight on x[h-1][w-1]
                    acc[i][0] += A0D * pm0;
                    acc[i][1] += A0D * pm1;
                }
                pm0 = pc0; pm1 = pc1; pc0 = pn0; pc1 = pn1;
            }
        }

        // pack to bf16, write swizzled: byte ^= ((w&7)<<4)
#pragma unroll
        for (int i = 0; i < 4; ++i) {
            const int w = wl0 + i;        // local row in [0,32)
            union { short8 v; unsigned short u[8]; } pk;
#pragma unroll
            for (int j = 0; j < 4; ++j) {
                pk.u[j]     = f2bf(acc[i][0][j]);
                pk.u[4 + j] = f2bf(acc[i][1][j]);
            }
            unsigned baddr = ((unsigned)w * 512u + (unsigned)c0 * 2u) ^ (((unsigned)(w & 7)) << 4);
            *reinterpret_cast<short8*>(reinterpret_cast<char*>(ylds) + baddr) = pk.v;
        }
    }
    __syncthreads();

    // ---------------- GEMM phase: out[32,256] = y @ Wm^T + b ----------------
    {
        const int wave = t >> 6;          // 0..3 -> N quarter [wave*64, +64)
        const int lane = t & 63;
        const int lrow = lane & 15;
        const int lkg  = lane >> 4;       // 0..3 k-group
        const int n_base = wave * 64;

        const f32x4 z = {0.f, 0.f, 0.f, 0.f};
        f32x4 acc2[2][4];                 // [mi(pixel block)][ni(e block)]
#pragma unroll
        for (int mi = 0; mi < 2; ++mi)
#pragma unroll
            for (int ni = 0; ni < 4; ++ni) acc2[mi][ni] = z;

        for (int k0 = 0; k0 < 256; k0 += 32) {
            const int koff = k0 + lkg * 8;
            short8 a[2], bf[4];
#pragma unroll
            for (int mi = 0; mi < 2; ++mi) {
                const int row = mi * 16 + lrow;
                unsigned baddr = ((unsigned)row * 512u + (unsigned)koff * 2u) ^ (((unsigned)(row & 7)) << 4);
                a[mi] = *reinterpret_cast<const short8*>(reinterpret_cast<const char*>(ylds) + baddr);
            }
#pragma unroll
            for (int ni = 0; ni < 4; ++ni) {
                const int e = n_base + ni * 16 + lrow;
                bf[ni] = *reinterpret_cast<const short8*>(Wm + e * 256 + koff);
            }
            // operand-swapped: D = W-frag (A) * y-frag (B) -> D[e][pixel];
            // lane holds e = ni*16 + lkg*4 + 0..3 (consecutive) for pixel mi*16+lrow
#pragma unroll
            for (int mi = 0; mi < 2; ++mi)
#pragma unroll
                for (int ni = 0; ni < 4; ++ni)
                    acc2[mi][ni] = __builtin_amdgcn_mfma_f32_16x16x32_bf16(bf[ni], a[mi], acc2[mi][ni], 0, 0, 0);
        }

        // epilogue: vector bias + f32x4 nontemporal stores
        const size_t outbase = (((size_t)b * 64 + h) * 64 + wbase) * 256;
        f32x4 bias4[4];
#pragma unroll
        for (int ni = 0; ni < 4; ++ni)
            bias4[ni] = *reinterpret_cast<const f32x4*>(proj_b + n_base + ni * 16 + lkg * 4);

#pragma unroll
        for (int mi = 0; mi < 2; ++mi) {
            const int pixel = mi * 16 + lrow;   // local pixel in [0,32)
            float* orow = out + outbase + (size_t)pixel * 256 + n_base + lkg * 4;
#pragma unroll
            for (int ni = 0; ni < 4; ++ni) {
                f32x4 v = acc2[mi][ni] + bias4[ni];
                __builtin_nontemporal_store(v, reinterpret_cast<f32x4*>(orow + ni * 16));
            }
        }
    }
}

extern "C" void kernel_launch(void* const* d_in, const int* in_sizes, int n_in,
                              void* d_out, int out_size, void* d_ws, size_t ws_size,
                              hipStream_t stream) {
    const float* x      = (const float*)d_in[0];
    const float* v_w    = (const float*)d_in[1];
    const float* proj_w = (const float*)d_in[2];
    const float* proj_b = (const float*)d_in[3];
    float* out = (float*)d_out;
    unsigned short* Wm = (unsigned short*)d_ws;   // 256*256 bf16 = 128 KB

    wmat_kernel<<<256, 1024, 0, stream>>>(v_w, proj_w, Wm);
    fused_kernel<<<1024, 256, 0, stream>>>(x, Wm, proj_b, out);
}